// Round 9
// baseline (44.396 us; speedup 1.0000x reference)
//
#include <hip/hip_runtime.h>
#include <hip/hip_bf16.h>

// B=64, S=512, N=32768, D=256, H=4, HD=64, T=24, scale=1/8.
//
// INSTRUMENTATION ROUND: launches K1,K2,K1,K2 (all idempotent) to measure
// K1+K2+2*gap as dur_delta vs round 8's single K1,K2. Bodies identical to r8.
//
// Workspace (float offsets):
//   qu  [64][256] f32   @ 0      (16384)
//   kk  [96][64]  f32   @ 16384  (6144)   (h*24+t, hd)
//   ET  [24][96]  f32   @ 22528  (2304)   exp(scale * qt . kk)
//   vWB 96x256 bf16     @ 24832  (12288 f32 words) folded V*Wu, MFMA-B frag layout
#define QU_OFF   0
#define KK_OFF   16384
#define ET_OFF   22528
#define VWB_OFF  24832

typedef __attribute__((ext_vector_type(8))) short bf16x8;
typedef __attribute__((ext_vector_type(4))) float f32x4;
typedef __attribute__((ext_vector_type(4))) int   i32x4;

__device__ __forceinline__ unsigned short f2bf(float f) {
    unsigned u = __builtin_bit_cast(unsigned, f);
    return (unsigned short)((u + 0x7FFFu + ((u >> 16) & 1u)) >> 16);
}
__device__ __forceinline__ unsigned packbf(float a, float b) {
    return (unsigned)f2bf(a) | ((unsigned)f2bf(b) << 16);
}
__device__ __forceinline__ bf16x8 cvt8(float4 f0, float4 f1) {
    int4 v = make_int4(packbf(f0.x, f0.y), packbf(f0.z, f0.w),
                       packbf(f1.x, f1.y), packbf(f1.z, f1.w));
    return __builtin_bit_cast(bf16x8, v);
}
__device__ __forceinline__ float dot4(float4 a, float4 b, float s) {
    return fmaf(a.x, b.x, fmaf(a.y, b.y, fmaf(a.z, b.z, fmaf(a.w, b.w, s))));
}
__device__ __forceinline__ float dot4v(f32x4 a, f32x4 b, float s) {
    return fmaf(a[0], b[0], fmaf(a[1], b[1], fmaf(a[2], b[2], fmaf(a[3], b[3], s))));
}

// Fragment conventions (validated end-to-end by the passing rounds):
//   A/B-frag 16x32: lane=(idx&15)+16*((k>>3)&3), u32 word=(k&7)>>1, half=k&1
//   D-frag: lane l, reg r -> row=(l>>4)*4+r, col=(l&15)

// ---------- K1: all precompute, 24 independent blocks ----------
__global__ __launch_bounds__(256) void precomp(
    const float* __restrict__ ts, const int* __restrict__ user,
    const float* __restrict__ user_pref,
    const float* __restrict__ Wq, const float* __restrict__ bq,
    const float* __restrict__ Wk, const float* __restrict__ bk,
    const float* __restrict__ Wv, const float* __restrict__ bv,
    const float* __restrict__ Wu, float* __restrict__ ws)
{
    __shared__ unsigned sA[4096];          // 16 KB: A-frags [(kt*2+mt)*64+lane]*4+word
    __shared__ float sM1[32 * 68];
    __shared__ float sM2[32 * 68];
    int tid = threadIdx.x, blk = blockIdx.x;
    int w = tid >> 6, l = tid & 63;
    int eo = (l >> 4) * 8;                 // per-lane k-offset within a frag

    if (blk < 16) {
        // ========== qu quarter: 16 users x 64 cols (1 N-tile/wave) ==========
        int q = blk >> 2, co = (blk & 3) * 64, b0 = q * 16;
        for (int u = tid; u < 512; u += 256) {       // stage 16 user rows
            int r = u >> 5, e0 = (u & 31) * 8;
            const float* src = user_pref + (size_t)user[b0 + r] * 256 + e0;
            float4 f0 = *(const float4*)src, f1 = *(const float4*)(src + 4);
            unsigned* dst = &sA[(((e0 >> 5) * 2) * 64 + (r & 15) + 16 * ((e0 >> 3) & 3)) * 4];
            dst[0] = packbf(f0.x, f0.y); dst[1] = packbf(f0.z, f0.w);
            dst[2] = packbf(f1.x, f1.y); dst[3] = packbf(f1.z, f1.w);
        }
        __syncthreads();
        int col = co + w * 16 + (l & 15);
        float4 fb[8][2];
        #pragma unroll
        for (int kt = 0; kt < 8; ++kt) {
            const float* Bp = Wq + (size_t)col * 512 + kt * 32 + eo;
            fb[kt][0] = *(const float4*)Bp; fb[kt][1] = *(const float4*)(Bp + 4);
        }
        f32x4 acc = (f32x4)0.f;
        #pragma unroll
        for (int kt = 0; kt < 8; ++kt) {
            bf16x8 afr = __builtin_bit_cast(bf16x8, *(const int4*)&sA[((kt * 2) * 64 + l) * 4]);
            acc = __builtin_amdgcn_mfma_f32_16x16x32_bf16(afr, cvt8(fb[kt][0], fb[kt][1]), acc, 0, 0, 0);
        }
        int row = (l >> 4) * 4;
        #pragma unroll
        for (int r = 0; r < 4; ++r)
            ws[QU_OFF + (size_t)(b0 + row + r) * 256 + col] = acc[r];
        return;
    }

    // ---- blocks 16..23 stage ts[24][256] as A-frags (rows 24..31 unused) ----
    for (int u = tid; u < 768; u += 256) {
        int r = u >> 5, e0 = (u & 31) * 8;
        const float* src = ts + r * 256 + e0;
        float4 f0 = *(const float4*)src, f1 = *(const float4*)(src + 4);
        unsigned* dst = &sA[(((e0 >> 5) * 2 + (r >> 4)) * 64 + (r & 15) + 16 * ((e0 >> 3) & 3)) * 4];
        dst[0] = packbf(f0.x, f0.y); dst[1] = packbf(f0.z, f0.w);
        dst[2] = packbf(f1.x, f1.y); dst[3] = packbf(f1.z, f1.w);
    }
    __syncthreads();

    if (blk < 20) {
        // ============ qk-chain h: qt_h, kk_h -> ET[t'][h*24+t] ============
        int h = blk - 16;
        int j = h * 64 + w * 16 + (l & 15);          // head-dim col
        float4 fa[8][2], fc[8][2];
        #pragma unroll
        for (int kt = 0; kt < 8; ++kt) {
            const float* Bq = Wq + (size_t)j * 512 + 256 + kt * 32 + eo;
            const float* Bk = Wk + (size_t)j * 256 + kt * 32 + eo;
            fa[kt][0] = *(const float4*)Bq; fa[kt][1] = *(const float4*)(Bq + 4);
            fc[kt][0] = *(const float4*)Bk; fc[kt][1] = *(const float4*)(Bk + 4);
        }
        f32x4 aca[2] = {(f32x4)0.f, (f32x4)0.f};
        f32x4 acb[2] = {(f32x4)0.f, (f32x4)0.f};
        #pragma unroll
        for (int kt = 0; kt < 8; ++kt) {
            bf16x8 bq8 = cvt8(fa[kt][0], fa[kt][1]);
            bf16x8 bk8 = cvt8(fc[kt][0], fc[kt][1]);
            #pragma unroll
            for (int mt = 0; mt < 2; ++mt) {
                bf16x8 afr = __builtin_bit_cast(bf16x8, *(const int4*)&sA[((kt * 2 + mt) * 64 + l) * 4]);
                aca[mt] = __builtin_amdgcn_mfma_f32_16x16x32_bf16(afr, bq8, aca[mt], 0, 0, 0);
                acb[mt] = __builtin_amdgcn_mfma_f32_16x16x32_bf16(afr, bk8, acb[mt], 0, 0, 0);
            }
        }
        float bqv = bq[j], bkv = bk[j];
        int hd = w * 16 + (l & 15);
        #pragma unroll
        for (int mt = 0; mt < 2; ++mt) {
            int t0 = mt * 16 + (l >> 4) * 4;
            #pragma unroll
            for (int r = 0; r < 4; ++r) {
                int t = t0 + r;
                if (t < 24) {
                    sM1[t * 68 + hd] = aca[mt][r] + bqv;
                    float kv = acb[mt][r] + bkv;
                    sM2[t * 68 + hd] = kv;
                    ws[KK_OFF + (h * 24 + t) * 64 + hd] = kv;
                }
            }
        }
        __syncthreads();
        for (int u = tid; u < 576; u += 256) {       // ET: 24x24 dot-64
            int tp = u / 24, t = u - tp * 24;
            const float4* qp4 = (const float4*)&sM1[tp * 68];
            const float4* kp4 = (const float4*)&sM2[t * 68];
            float s = 0.f;
            #pragma unroll
            for (int i = 0; i < 16; ++i) s = dot4(qp4[i], kp4[i], s);
            ws[ET_OFF + tp * 96 + h * 24 + t] = expf(s * 0.125f);
        }
        return;
    }

    // ============== v-chain h: vv_h -> vW_h -> vWB (B-frag) ==============
    {
        int h = blk - 20;
        int jv = h * 64 + w * 16 + (l & 15);
        float4 fv[8][2];
        #pragma unroll
        for (int kt = 0; kt < 8; ++kt) {
            const float* Bv = Wv + (size_t)jv * 256 + kt * 32 + eo;
            fv[kt][0] = *(const float4*)Bv; fv[kt][1] = *(const float4*)(Bv + 4);
        }
        f32x4 acv[2] = {(f32x4)0.f, (f32x4)0.f};
        #pragma unroll
        for (int kt = 0; kt < 8; ++kt) {
            bf16x8 bv8 = cvt8(fv[kt][0], fv[kt][1]);
            #pragma unroll
            for (int mt = 0; mt < 2; ++mt) {
                bf16x8 afr = __builtin_bit_cast(bf16x8, *(const int4*)&sA[((kt * 2 + mt) * 64 + l) * 4]);
                acv[mt] = __builtin_amdgcn_mfma_f32_16x16x32_bf16(afr, bv8, acv[mt], 0, 0, 0);
            }
        }
        float bvv = bv[jv];
        int hd = w * 16 + (l & 15);
        #pragma unroll
        for (int mt = 0; mt < 2; ++mt) {
            int t0 = mt * 16 + (l >> 4) * 4;
            #pragma unroll
            for (int r = 0; r < 4; ++r)
                if (t0 + r < 24) sM1[(t0 + r) * 68 + hd] = acv[mt][r] + bvv;
        }
        __syncthreads();
        // GEMM2: vW = vv[24(p32) x 64] @ WuCols^T -> vWB (B-frag layout)
        f32x4 ac2[2][4];
        #pragma unroll
        for (int mt = 0; mt < 2; ++mt)
            #pragma unroll
            for (int q = 0; q < 4; ++q) ac2[mt][q] = (f32x4)0.f;
        #pragma unroll
        for (int kt2 = 0; kt2 < 2; ++kt2) {
            int k0 = kt2 * 32 + eo;
            bf16x8 a2[2];
            #pragma unroll
            for (int mt = 0; mt < 2; ++mt) {
                int m = mt * 16 + (l & 15);
                float4 g0 = *(const float4*)&sM1[m * 68 + k0];
                float4 g1 = *(const float4*)&sM1[m * 68 + k0 + 4];
                a2[mt] = cvt8(g0, g1);
            }
            float4 fu[4][2];
            #pragma unroll
            for (int q = 0; q < 4; ++q) {
                int d = (w * 4 + q) * 16 + (l & 15);
                const float* Bu = Wu + (size_t)d * 256 + h * 64 + k0;
                fu[q][0] = *(const float4*)Bu; fu[q][1] = *(const float4*)(Bu + 4);
            }
            #pragma unroll
            for (int q = 0; q < 4; ++q) {
                bf16x8 bu8 = cvt8(fu[q][0], fu[q][1]);
                #pragma unroll
                for (int mt = 0; mt < 2; ++mt)
                    ac2[mt][q] = __builtin_amdgcn_mfma_f32_16x16x32_bf16(a2[mt], bu8, ac2[mt][q], 0, 0, 0);
            }
        }
        unsigned* vwb = (unsigned*)(ws + VWB_OFF);
        #pragma unroll
        for (int mt = 0; mt < 2; ++mt) {
            int t0 = mt * 16 + (l >> 4) * 4;
            if (t0 < 24) {
                #pragma unroll
                for (int q = 0; q < 4; ++q) {
                    int d = (w * 4 + q) * 16 + (l & 15);
                    #pragma unroll
                    for (int pp = 0; pp < 2; ++pp) {
                        int ht = h * 24 + t0 + pp * 2;       // even
                        unsigned pk = packbf(ac2[mt][q][pp * 2], ac2[mt][q][pp * 2 + 1]);
                        int ktC = ht >> 5, ntC = d >> 4;
                        int lgC = (ht >> 3) & 3, jhC = (ht & 7) >> 1;
                        vwb[(ktC * 16 + ntC) * 256 + ((d & 15) + 16 * lgC) * 4 + jhC] = pk;
                    }
                }
            }
        }
    }
}

// ---------- K2: 128 tok/block, 512 thr; prefetch-first; MFMA; NT vector stores ----------
__global__ __launch_bounds__(512) void attn_mfma(
    const int* __restrict__ hour, const int* __restrict__ hour_mask,
    const float* __restrict__ ws, const float* __restrict__ bu,
    float* __restrict__ out)
{
    const float* ET = ws + ET_OFF;
    __shared__ int4 A_lds[24 * 64];                    // 24 KB
    __shared__ float EU_s[96];
    __shared__ __align__(16) float stg[8 * 1088];      // 8 waves x [16][68] f32
    int tid = threadIdx.x, w = tid >> 6, l = tid & 63;
    int mh = w >> 2, ns = w & 3;
    int nb = blockIdx.x * 128;                // 128 tokens/block, same b
    int b = nb >> 9;

    // ---- (1) longest-latency loads first: hour, mask (nontemporal) ----
    int tok = tid >> 2, h = tid & 3, n = nb + tok;
    int th = hour[n];
    const i32x4* mp = (const i32x4*)(hour_mask + (long long)n * 24);
    i32x4 msk[6];
    #pragma unroll
    for (int q = 0; q < 6; ++q) msk[q] = __builtin_nontemporal_load(mp + q);
    // ---- (2) B fragments (L2-resident table) ----
    const int4* Bg = (const int4*)(ws + VWB_OFF);
    int4 breg[12];
    #pragma unroll
    for (int kt = 0; kt < 3; ++kt)
        #pragma unroll
        for (int q = 0; q < 4; ++q)
            breg[kt * 4 + q] = Bg[(kt * 16 + ns * 4 + q) * 64 + l];
    // ---- (3) EU[ht] for this block's b ----
    if (tid < 96) {
        const f32x4* qp = (const f32x4*)(ws + QU_OFF + b * 256 + (tid / 24) * 64);
        const f32x4* kp = (const f32x4*)(ws + KK_OFF + tid * 64);
        float s = 0.f;
        #pragma unroll
        for (int i = 0; i < 16; ++i) s = dot4v(qp[i], kp[i], s);
        EU_s[tid] = expf(s * 0.125f);
    }
    // ---- (4) ET row (depends on th, long since arrived) ----
    const f32x4* ETp = (const f32x4*)(ET + th * 96 + h * 24);
    f32x4 fET[6];
    #pragma unroll
    for (int q = 0; q < 6; ++q) fET[q] = ETp[q];
    __syncthreads();
    // ---- (5) softmax (no exp) -> bf16 A-fragments in LDS ----
    {
        const f32x4* EUp = (const f32x4*)(EU_s + h * 24);
        float p[24]; float ssum = 0.f;
        #pragma unroll
        for (int q = 0; q < 6; ++q) {
            f32x4 e = EUp[q]; f32x4 f = fET[q]; i32x4 mm = msk[q];
            float v0 = (mm[0] != 0) ? 0.f : e[0] * f[0];
            float v1 = (mm[1] != 0) ? 0.f : e[1] * f[1];
            float v2 = (mm[2] != 0) ? 0.f : e[2] * f[2];
            float v3 = (mm[3] != 0) ? 0.f : e[3] * f[3];
            p[q*4+0] = v0; p[q*4+1] = v1; p[q*4+2] = v2; p[q*4+3] = v3;
            ssum += (v0 + v1) + (v2 + v3);
        }
        float r = 1.0f / ssum;
        int mt8 = tok >> 4, tl = tok & 15;
        #pragma unroll
        for (int tp = 0; tp < 12; ++tp) {
            int ht = h * 24 + tp * 2;             // even; pair (ht, ht+1)
            unsigned pack = packbf(p[tp*2] * r, p[tp*2+1] * r);
            int kt = ht >> 5, lg = (ht >> 3) & 3, jh = (ht & 7) >> 1;
            ((unsigned*)A_lds)[((kt * 8 + mt8) * 64 + tl + 16 * lg) * 4 + jh] = pack;
        }
    }
    __syncthreads();
    // ---- (6) wave (mh,ns): 4 M-tiles x 4 N-tiles x 3 K-chunks MFMA ----
    bf16x8 afr[3][4];
    #pragma unroll
    for (int kt = 0; kt < 3; ++kt)
        #pragma unroll
        for (int q = 0; q < 4; ++q)
            afr[kt][q] = __builtin_bit_cast(bf16x8, A_lds[(kt * 8 + mh * 4 + q) * 64 + l]);
    f32x4 acc[4][4];
    #pragma unroll
    for (int mt = 0; mt < 4; ++mt)
        #pragma unroll
        for (int q = 0; q < 4; ++q) acc[mt][q] = (f32x4)0.f;
    #pragma unroll
    for (int kt = 0; kt < 3; ++kt)
        #pragma unroll
        for (int mt = 0; mt < 4; ++mt)
            #pragma unroll
            for (int q = 0; q < 4; ++q)
                acc[mt][q] = __builtin_amdgcn_mfma_f32_16x16x32_bf16(
                    afr[kt][mt], __builtin_bit_cast(bf16x8, breg[kt * 4 + q]),
                    acc[mt][q], 0, 0, 0);
    // ---- (7) epilogue: per-wave LDS transpose -> +bu -> NT f32x4 stores ----
    float* sp = stg + w * 1088;
    int rr = l >> 2, cg = l & 3;
    f32x4 bu4[4];
    #pragma unroll
    for (int i = 0; i < 4; ++i)
        bu4[i] = *(const f32x4*)(bu + ns * 64 + i * 16 + cg * 4);
    int rbase = nb + mh * 64;
    #pragma unroll
    for (int mt = 0; mt < 4; ++mt) {
        #pragma unroll
        for (int q = 0; q < 4; ++q)
            #pragma unroll
            for (int r = 0; r < 4; ++r)
                sp[((l >> 4) * 4 + r) * 68 + q * 16 + (l & 15)] = acc[mt][q][r];
        float* orow = out + (size_t)(rbase + mt * 16 + rr) * 256 + ns * 64;
        #pragma unroll
        for (int i = 0; i < 4; ++i) {
            f32x4 v = *(const f32x4*)(sp + rr * 68 + i * 16 + cg * 4);
            v = v + bu4[i];
            __builtin_nontemporal_store(v, (f32x4*)(orow + i * 16 + cg * 4));
        }
    }
}

extern "C" void kernel_launch(void* const* d_in, const int* in_sizes, int n_in,
                              void* d_out, int out_size, void* d_ws, size_t ws_size,
                              hipStream_t stream)
{
    const float* ts        = (const float*)d_in[0];
    const int*   user      = (const int*)  d_in[1];
    const int*   hour      = (const int*)  d_in[2];
    const int*   hour_mask = (const int*)  d_in[3];
    const float* user_pref = (const float*)d_in[4];
    const float* Wq        = (const float*)d_in[5];
    const float* bq        = (const float*)d_in[6];
    const float* Wk        = (const float*)d_in[7];
    const float* bk        = (const float*)d_in[8];
    const float* Wv        = (const float*)d_in[9];
    const float* bv        = (const float*)d_in[10];
    const float* Wu        = (const float*)d_in[11];
    const float* bu        = (const float*)d_in[12];
    float* ws  = (float*)d_ws;
    float* out = (float*)d_out;

    // INSTRUMENTATION: run the (idempotent) pair twice. dur_delta vs r8
    // = K1 + K2 + 2 node gaps, measured on-chip.
    hipLaunchKernelGGL(precomp, dim3(24), dim3(256), 0, stream,
                       ts, user, user_pref, Wq, bq, Wk, bk, Wv, bv, Wu, ws);
    hipLaunchKernelGGL(attn_mfma, dim3(256), dim3(512), 0, stream,
                       hour, hour_mask, ws, bu, out);
    hipLaunchKernelGGL(precomp, dim3(24), dim3(256), 0, stream,
                       ts, user, user_pref, Wq, bq, Wk, bk, Wv, bv, Wu, ws);
    hipLaunchKernelGGL(attn_mfma, dim3(256), dim3(512), 0, stream,
                       hour, hour_mask, ws, bu, out);
}

// Round 10
// 36.498 us; speedup vs baseline: 1.2164x; 1.2164x over previous
//
#include <hip/hip_runtime.h>
#include <hip/hip_bf16.h>

// B=64, S=512, N=32768, D=256, H=4, HD=64, T=24, scale=1/8.
//
// INSTRUMENTATION ROUND 2: launches K1, K2, K2 (K2 idempotent).
// dur_delta vs round 8 (K1,K2) = K2 + gap -> pins the K1/K2 split.
//
// Workspace (float offsets):
//   qu  [64][256] f32   @ 0      (16384)
//   kk  [96][64]  f32   @ 16384  (6144)   (h*24+t, hd)
//   ET  [24][96]  f32   @ 22528  (2304)   exp(scale * qt . kk)
//   vWB 96x256 bf16     @ 24832  (12288 f32 words) folded V*Wu, MFMA-B frag layout
#define QU_OFF   0
#define KK_OFF   16384
#define ET_OFF   22528
#define VWB_OFF  24832

typedef __attribute__((ext_vector_type(8))) short bf16x8;
typedef __attribute__((ext_vector_type(4))) float f32x4;
typedef __attribute__((ext_vector_type(4))) int   i32x4;

__device__ __forceinline__ unsigned short f2bf(float f) {
    unsigned u = __builtin_bit_cast(unsigned, f);
    return (unsigned short)((u + 0x7FFFu + ((u >> 16) & 1u)) >> 16);
}
__device__ __forceinline__ unsigned packbf(float a, float b) {
    return (unsigned)f2bf(a) | ((unsigned)f2bf(b) << 16);
}
__device__ __forceinline__ bf16x8 cvt8(float4 f0, float4 f1) {
    int4 v = make_int4(packbf(f0.x, f0.y), packbf(f0.z, f0.w),
                       packbf(f1.x, f1.y), packbf(f1.z, f1.w));
    return __builtin_bit_cast(bf16x8, v);
}
__device__ __forceinline__ float dot4(float4 a, float4 b, float s) {
    return fmaf(a.x, b.x, fmaf(a.y, b.y, fmaf(a.z, b.z, fmaf(a.w, b.w, s))));
}
__device__ __forceinline__ float dot4v(f32x4 a, f32x4 b, float s) {
    return fmaf(a[0], b[0], fmaf(a[1], b[1], fmaf(a[2], b[2], fmaf(a[3], b[3], s))));
}

// Fragment conventions (validated end-to-end by the passing rounds):
//   A/B-frag 16x32: lane=(idx&15)+16*((k>>3)&3), u32 word=(k&7)>>1, half=k&1
//   D-frag: lane l, reg r -> row=(l>>4)*4+r, col=(l&15)

// ---------- K1: all precompute, 24 independent blocks ----------
__global__ __launch_bounds__(256) void precomp(
    const float* __restrict__ ts, const int* __restrict__ user,
    const float* __restrict__ user_pref,
    const float* __restrict__ Wq, const float* __restrict__ bq,
    const float* __restrict__ Wk, const float* __restrict__ bk,
    const float* __restrict__ Wv, const float* __restrict__ bv,
    const float* __restrict__ Wu, float* __restrict__ ws)
{
    __shared__ unsigned sA[4096];          // 16 KB: A-frags [(kt*2+mt)*64+lane]*4+word
    __shared__ float sM1[32 * 68];
    __shared__ float sM2[32 * 68];
    int tid = threadIdx.x, blk = blockIdx.x;
    int w = tid >> 6, l = tid & 63;
    int eo = (l >> 4) * 8;                 // per-lane k-offset within a frag

    if (blk < 16) {
        // ========== qu quarter: 16 users x 64 cols (1 N-tile/wave) ==========
        int q = blk >> 2, co = (blk & 3) * 64, b0 = q * 16;
        for (int u = tid; u < 512; u += 256) {       // stage 16 user rows
            int r = u >> 5, e0 = (u & 31) * 8;
            const float* src = user_pref + (size_t)user[b0 + r] * 256 + e0;
            float4 f0 = *(const float4*)src, f1 = *(const float4*)(src + 4);
            unsigned* dst = &sA[(((e0 >> 5) * 2) * 64 + (r & 15) + 16 * ((e0 >> 3) & 3)) * 4];
            dst[0] = packbf(f0.x, f0.y); dst[1] = packbf(f0.z, f0.w);
            dst[2] = packbf(f1.x, f1.y); dst[3] = packbf(f1.z, f1.w);
        }
        __syncthreads();
        int col = co + w * 16 + (l & 15);
        float4 fb[8][2];
        #pragma unroll
        for (int kt = 0; kt < 8; ++kt) {
            const float* Bp = Wq + (size_t)col * 512 + kt * 32 + eo;
            fb[kt][0] = *(const float4*)Bp; fb[kt][1] = *(const float4*)(Bp + 4);
        }
        f32x4 acc = (f32x4)0.f;
        #pragma unroll
        for (int kt = 0; kt < 8; ++kt) {
            bf16x8 afr = __builtin_bit_cast(bf16x8, *(const int4*)&sA[((kt * 2) * 64 + l) * 4]);
            acc = __builtin_amdgcn_mfma_f32_16x16x32_bf16(afr, cvt8(fb[kt][0], fb[kt][1]), acc, 0, 0, 0);
        }
        int row = (l >> 4) * 4;
        #pragma unroll
        for (int r = 0; r < 4; ++r)
            ws[QU_OFF + (size_t)(b0 + row + r) * 256 + col] = acc[r];
        return;
    }

    // ---- blocks 16..23 stage ts[24][256] as A-frags (rows 24..31 unused) ----
    for (int u = tid; u < 768; u += 256) {
        int r = u >> 5, e0 = (u & 31) * 8;
        const float* src = ts + r * 256 + e0;
        float4 f0 = *(const float4*)src, f1 = *(const float4*)(src + 4);
        unsigned* dst = &sA[(((e0 >> 5) * 2 + (r >> 4)) * 64 + (r & 15) + 16 * ((e0 >> 3) & 3)) * 4];
        dst[0] = packbf(f0.x, f0.y); dst[1] = packbf(f0.z, f0.w);
        dst[2] = packbf(f1.x, f1.y); dst[3] = packbf(f1.z, f1.w);
    }
    __syncthreads();

    if (blk < 20) {
        // ============ qk-chain h: qt_h, kk_h -> ET[t'][h*24+t] ============
        int h = blk - 16;
        int j = h * 64 + w * 16 + (l & 15);          // head-dim col
        float4 fa[8][2], fc[8][2];
        #pragma unroll
        for (int kt = 0; kt < 8; ++kt) {
            const float* Bq = Wq + (size_t)j * 512 + 256 + kt * 32 + eo;
            const float* Bk = Wk + (size_t)j * 256 + kt * 32 + eo;
            fa[kt][0] = *(const float4*)Bq; fa[kt][1] = *(const float4*)(Bq + 4);
            fc[kt][0] = *(const float4*)Bk; fc[kt][1] = *(const float4*)(Bk + 4);
        }
        f32x4 aca[2] = {(f32x4)0.f, (f32x4)0.f};
        f32x4 acb[2] = {(f32x4)0.f, (f32x4)0.f};
        #pragma unroll
        for (int kt = 0; kt < 8; ++kt) {
            bf16x8 bq8 = cvt8(fa[kt][0], fa[kt][1]);
            bf16x8 bk8 = cvt8(fc[kt][0], fc[kt][1]);
            #pragma unroll
            for (int mt = 0; mt < 2; ++mt) {
                bf16x8 afr = __builtin_bit_cast(bf16x8, *(const int4*)&sA[((kt * 2 + mt) * 64 + l) * 4]);
                aca[mt] = __builtin_amdgcn_mfma_f32_16x16x32_bf16(afr, bq8, aca[mt], 0, 0, 0);
                acb[mt] = __builtin_amdgcn_mfma_f32_16x16x32_bf16(afr, bk8, acb[mt], 0, 0, 0);
            }
        }
        float bqv = bq[j], bkv = bk[j];
        int hd = w * 16 + (l & 15);
        #pragma unroll
        for (int mt = 0; mt < 2; ++mt) {
            int t0 = mt * 16 + (l >> 4) * 4;
            #pragma unroll
            for (int r = 0; r < 4; ++r) {
                int t = t0 + r;
                if (t < 24) {
                    sM1[t * 68 + hd] = aca[mt][r] + bqv;
                    float kv = acb[mt][r] + bkv;
                    sM2[t * 68 + hd] = kv;
                    ws[KK_OFF + (h * 24 + t) * 64 + hd] = kv;
                }
            }
        }
        __syncthreads();
        for (int u = tid; u < 576; u += 256) {       // ET: 24x24 dot-64
            int tp = u / 24, t = u - tp * 24;
            const float4* qp4 = (const float4*)&sM1[tp * 68];
            const float4* kp4 = (const float4*)&sM2[t * 68];
            float s = 0.f;
            #pragma unroll
            for (int i = 0; i < 16; ++i) s = dot4(qp4[i], kp4[i], s);
            ws[ET_OFF + tp * 96 + h * 24 + t] = expf(s * 0.125f);
        }
        return;
    }

    // ============== v-chain h: vv_h -> vW_h -> vWB (B-frag) ==============
    {
        int h = blk - 20;
        int jv = h * 64 + w * 16 + (l & 15);
        float4 fv[8][2];
        #pragma unroll
        for (int kt = 0; kt < 8; ++kt) {
            const float* Bv = Wv + (size_t)jv * 256 + kt * 32 + eo;
            fv[kt][0] = *(const float4*)Bv; fv[kt][1] = *(const float4*)(Bv + 4);
        }
        f32x4 acv[2] = {(f32x4)0.f, (f32x4)0.f};
        #pragma unroll
        for (int kt = 0; kt < 8; ++kt) {
            bf16x8 bv8 = cvt8(fv[kt][0], fv[kt][1]);
            #pragma unroll
            for (int mt = 0; mt < 2; ++mt) {
                bf16x8 afr = __builtin_bit_cast(bf16x8, *(const int4*)&sA[((kt * 2 + mt) * 64 + l) * 4]);
                acv[mt] = __builtin_amdgcn_mfma_f32_16x16x32_bf16(afr, bv8, acv[mt], 0, 0, 0);
            }
        }
        float bvv = bv[jv];
        int hd = w * 16 + (l & 15);
        #pragma unroll
        for (int mt = 0; mt < 2; ++mt) {
            int t0 = mt * 16 + (l >> 4) * 4;
            #pragma unroll
            for (int r = 0; r < 4; ++r)
                if (t0 + r < 24) sM1[(t0 + r) * 68 + hd] = acv[mt][r] + bvv;
        }
        __syncthreads();
        // GEMM2: vW = vv[24(p32) x 64] @ WuCols^T -> vWB (B-frag layout)
        f32x4 ac2[2][4];
        #pragma unroll
        for (int mt = 0; mt < 2; ++mt)
            #pragma unroll
            for (int q = 0; q < 4; ++q) ac2[mt][q] = (f32x4)0.f;
        #pragma unroll
        for (int kt2 = 0; kt2 < 2; ++kt2) {
            int k0 = kt2 * 32 + eo;
            bf16x8 a2[2];
            #pragma unroll
            for (int mt = 0; mt < 2; ++mt) {
                int m = mt * 16 + (l & 15);
                float4 g0 = *(const float4*)&sM1[m * 68 + k0];
                float4 g1 = *(const float4*)&sM1[m * 68 + k0 + 4];
                a2[mt] = cvt8(g0, g1);
            }
            float4 fu[4][2];
            #pragma unroll
            for (int q = 0; q < 4; ++q) {
                int d = (w * 4 + q) * 16 + (l & 15);
                const float* Bu = Wu + (size_t)d * 256 + h * 64 + k0;
                fu[q][0] = *(const float4*)Bu; fu[q][1] = *(const float4*)(Bu + 4);
            }
            #pragma unroll
            for (int q = 0; q < 4; ++q) {
                bf16x8 bu8 = cvt8(fu[q][0], fu[q][1]);
                #pragma unroll
                for (int mt = 0; mt < 2; ++mt)
                    ac2[mt][q] = __builtin_amdgcn_mfma_f32_16x16x32_bf16(a2[mt], bu8, ac2[mt][q], 0, 0, 0);
            }
        }
        unsigned* vwb = (unsigned*)(ws + VWB_OFF);
        #pragma unroll
        for (int mt = 0; mt < 2; ++mt) {
            int t0 = mt * 16 + (l >> 4) * 4;
            if (t0 < 24) {
                #pragma unroll
                for (int q = 0; q < 4; ++q) {
                    int d = (w * 4 + q) * 16 + (l & 15);
                    #pragma unroll
                    for (int pp = 0; pp < 2; ++pp) {
                        int ht = h * 24 + t0 + pp * 2;       // even
                        unsigned pk = packbf(ac2[mt][q][pp * 2], ac2[mt][q][pp * 2 + 1]);
                        int ktC = ht >> 5, ntC = d >> 4;
                        int lgC = (ht >> 3) & 3, jhC = (ht & 7) >> 1;
                        vwb[(ktC * 16 + ntC) * 256 + ((d & 15) + 16 * lgC) * 4 + jhC] = pk;
                    }
                }
            }
        }
    }
}

// ---------- K2: 128 tok/block, 512 thr; prefetch-first; MFMA; NT vector stores ----------
__global__ __launch_bounds__(512) void attn_mfma(
    const int* __restrict__ hour, const int* __restrict__ hour_mask,
    const float* __restrict__ ws, const float* __restrict__ bu,
    float* __restrict__ out)
{
    const float* ET = ws + ET_OFF;
    __shared__ int4 A_lds[24 * 64];                    // 24 KB
    __shared__ float EU_s[96];
    __shared__ __align__(16) float stg[8 * 1088];      // 8 waves x [16][68] f32
    int tid = threadIdx.x, w = tid >> 6, l = tid & 63;
    int mh = w >> 2, ns = w & 3;
    int nb = blockIdx.x * 128;                // 128 tokens/block, same b
    int b = nb >> 9;

    // ---- (1) longest-latency loads first: hour, mask (nontemporal) ----
    int tok = tid >> 2, h = tid & 3, n = nb + tok;
    int th = hour[n];
    const i32x4* mp = (const i32x4*)(hour_mask + (long long)n * 24);
    i32x4 msk[6];
    #pragma unroll
    for (int q = 0; q < 6; ++q) msk[q] = __builtin_nontemporal_load(mp + q);
    // ---- (2) B fragments (L2-resident table) ----
    const int4* Bg = (const int4*)(ws + VWB_OFF);
    int4 breg[12];
    #pragma unroll
    for (int kt = 0; kt < 3; ++kt)
        #pragma unroll
        for (int q = 0; q < 4; ++q)
            breg[kt * 4 + q] = Bg[(kt * 16 + ns * 4 + q) * 64 + l];
    // ---- (3) EU[ht] for this block's b ----
    if (tid < 96) {
        const f32x4* qp = (const f32x4*)(ws + QU_OFF + b * 256 + (tid / 24) * 64);
        const f32x4* kp = (const f32x4*)(ws + KK_OFF + tid * 64);
        float s = 0.f;
        #pragma unroll
        for (int i = 0; i < 16; ++i) s = dot4v(qp[i], kp[i], s);
        EU_s[tid] = expf(s * 0.125f);
    }
    // ---- (4) ET row (depends on th, long since arrived) ----
    const f32x4* ETp = (const f32x4*)(ET + th * 96 + h * 24);
    f32x4 fET[6];
    #pragma unroll
    for (int q = 0; q < 6; ++q) fET[q] = ETp[q];
    __syncthreads();
    // ---- (5) softmax (no exp) -> bf16 A-fragments in LDS ----
    {
        const f32x4* EUp = (const f32x4*)(EU_s + h * 24);
        float p[24]; float ssum = 0.f;
        #pragma unroll
        for (int q = 0; q < 6; ++q) {
            f32x4 e = EUp[q]; f32x4 f = fET[q]; i32x4 mm = msk[q];
            float v0 = (mm[0] != 0) ? 0.f : e[0] * f[0];
            float v1 = (mm[1] != 0) ? 0.f : e[1] * f[1];
            float v2 = (mm[2] != 0) ? 0.f : e[2] * f[2];
            float v3 = (mm[3] != 0) ? 0.f : e[3] * f[3];
            p[q*4+0] = v0; p[q*4+1] = v1; p[q*4+2] = v2; p[q*4+3] = v3;
            ssum += (v0 + v1) + (v2 + v3);
        }
        float r = 1.0f / ssum;
        int mt8 = tok >> 4, tl = tok & 15;
        #pragma unroll
        for (int tp = 0; tp < 12; ++tp) {
            int ht = h * 24 + tp * 2;             // even; pair (ht, ht+1)
            unsigned pack = packbf(p[tp*2] * r, p[tp*2+1] * r);
            int kt = ht >> 5, lg = (ht >> 3) & 3, jh = (ht & 7) >> 1;
            ((unsigned*)A_lds)[((kt * 8 + mt8) * 64 + tl + 16 * lg) * 4 + jh] = pack;
        }
    }
    __syncthreads();
    // ---- (6) wave (mh,ns): 4 M-tiles x 4 N-tiles x 3 K-chunks MFMA ----
    bf16x8 afr[3][4];
    #pragma unroll
    for (int kt = 0; kt < 3; ++kt)
        #pragma unroll
        for (int q = 0; q < 4; ++q)
            afr[kt][q] = __builtin_bit_cast(bf16x8, A_lds[(kt * 8 + mh * 4 + q) * 64 + l]);
    f32x4 acc[4][4];
    #pragma unroll
    for (int mt = 0; mt < 4; ++mt)
        #pragma unroll
        for (int q = 0; q < 4; ++q) acc[mt][q] = (f32x4)0.f;
    #pragma unroll
    for (int kt = 0; kt < 3; ++kt)
        #pragma unroll
        for (int mt = 0; mt < 4; ++mt)
            #pragma unroll
            for (int q = 0; q < 4; ++q)
                acc[mt][q] = __builtin_amdgcn_mfma_f32_16x16x32_bf16(
                    afr[kt][mt], __builtin_bit_cast(bf16x8, breg[kt * 4 + q]),
                    acc[mt][q], 0, 0, 0);
    // ---- (7) epilogue: per-wave LDS transpose -> +bu -> NT f32x4 stores ----
    float* sp = stg + w * 1088;
    int rr = l >> 2, cg = l & 3;
    f32x4 bu4[4];
    #pragma unroll
    for (int i = 0; i < 4; ++i)
        bu4[i] = *(const f32x4*)(bu + ns * 64 + i * 16 + cg * 4);
    int rbase = nb + mh * 64;
    #pragma unroll
    for (int mt = 0; mt < 4; ++mt) {
        #pragma unroll
        for (int q = 0; q < 4; ++q)
            #pragma unroll
            for (int r = 0; r < 4; ++r)
                sp[((l >> 4) * 4 + r) * 68 + q * 16 + (l & 15)] = acc[mt][q][r];
        float* orow = out + (size_t)(rbase + mt * 16 + rr) * 256 + ns * 64;
        #pragma unroll
        for (int i = 0; i < 4; ++i) {
            f32x4 v = *(const f32x4*)(sp + rr * 68 + i * 16 + cg * 4);
            v = v + bu4[i];
            __builtin_nontemporal_store(v, (f32x4*)(orow + i * 16 + cg * 4));
        }
    }
}

extern "C" void kernel_launch(void* const* d_in, const int* in_sizes, int n_in,
                              void* d_out, int out_size, void* d_ws, size_t ws_size,
                              hipStream_t stream)
{
    const float* ts        = (const float*)d_in[0];
    const int*   user      = (const int*)  d_in[1];
    const int*   hour      = (const int*)  d_in[2];
    const int*   hour_mask = (const int*)  d_in[3];
    const float* user_pref = (const float*)d_in[4];
    const float* Wq        = (const float*)d_in[5];
    const float* bq        = (const float*)d_in[6];
    const float* Wk        = (const float*)d_in[7];
    const float* bk        = (const float*)d_in[8];
    const float* Wv        = (const float*)d_in[9];
    const float* bv        = (const float*)d_in[10];
    const float* Wu        = (const float*)d_in[11];
    const float* bu        = (const float*)d_in[12];
    float* ws  = (float*)d_ws;
    float* out = (float*)d_out;

    // INSTRUMENTATION: K1, K2, K2 (K2 idempotent). dur - r8 = K2 + gap.
    hipLaunchKernelGGL(precomp, dim3(24), dim3(256), 0, stream,
                       ts, user, user_pref, Wq, bq, Wk, bk, Wv, bv, Wu, ws);
    hipLaunchKernelGGL(attn_mfma, dim3(256), dim3(512), 0, stream,
                       hour, hour_mask, ws, bu, out);
    hipLaunchKernelGGL(attn_mfma, dim3(256), dim3(512), 0, stream,
                       hour, hour_mask, ws, bu, out);
}

// Round 11
// 24.206 us; speedup vs baseline: 1.8341x; 1.5078x over previous
//
#include <hip/hip_runtime.h>
#include <hip/hip_bf16.h>

// B=64, S=512, N=32768, D=256, H=4, HD=64, T=24, scale=1/8.
//
// Workspace (float offsets):
//   qu  [64][256] f32   @ 0      (16384)
//   kk  [96][64]  f32   @ 16384  (6144)   (h*24+t, hd)
//   ET  [24][96]  f32   @ 22528  (2304)   exp(scale * qt . kk)
//   vWB 96x256 bf16     @ 24832  (12288 f32 words) folded V*Wu, MFMA-B frag layout
#define QU_OFF   0
#define KK_OFF   16384
#define ET_OFF   22528
#define VWB_OFF  24832

typedef __attribute__((ext_vector_type(8))) short bf16x8;
typedef __attribute__((ext_vector_type(4))) float f32x4;
typedef __attribute__((ext_vector_type(4))) int   i32x4;

__device__ __forceinline__ unsigned short f2bf(float f) {
    unsigned u = __builtin_bit_cast(unsigned, f);
    return (unsigned short)((u + 0x7FFFu + ((u >> 16) & 1u)) >> 16);
}
__device__ __forceinline__ unsigned packbf(float a, float b) {
    return (unsigned)f2bf(a) | ((unsigned)f2bf(b) << 16);
}
__device__ __forceinline__ bf16x8 cvt8(float4 f0, float4 f1) {
    int4 v = make_int4(packbf(f0.x, f0.y), packbf(f0.z, f0.w),
                       packbf(f1.x, f1.y), packbf(f1.z, f1.w));
    return __builtin_bit_cast(bf16x8, v);
}
__device__ __forceinline__ float dot4(float4 a, float4 b, float s) {
    return fmaf(a.x, b.x, fmaf(a.y, b.y, fmaf(a.z, b.z, fmaf(a.w, b.w, s))));
}
__device__ __forceinline__ float dot4v(f32x4 a, f32x4 b, float s) {
    return fmaf(a[0], b[0], fmaf(a[1], b[1], fmaf(a[2], b[2], fmaf(a[3], b[3], s))));
}

// Fragment conventions (validated end-to-end by the passing rounds):
//   A/B-frag 16x32: lane=(idx&15)+16*((k>>3)&3), u32 word=(k&7)>>1, half=k&1
//   D-frag: lane l, reg r -> row=(l>>4)*4+r, col=(l&15)

// ---------- K1: all precompute, 24 blocks; WEIGHT LOADS ISSUED FIRST ----------
__global__ __launch_bounds__(256) void precomp(
    const float* __restrict__ ts, const int* __restrict__ user,
    const float* __restrict__ user_pref,
    const float* __restrict__ Wq, const float* __restrict__ bq,
    const float* __restrict__ Wk, const float* __restrict__ bk,
    const float* __restrict__ Wv, const float* __restrict__ bv,
    const float* __restrict__ Wu, float* __restrict__ ws)
{
    __shared__ unsigned sA[4096];          // 16 KB: A-frags [(kt*2+mt)*64+lane]*4+word
    __shared__ float sM1[32 * 68];
    __shared__ float sM2[32 * 68];
    int tid = threadIdx.x, blk = blockIdx.x;
    int w = tid >> 6, l = tid & 63;
    int eo = (l >> 4) * 8;                 // per-lane k-offset within a frag

    if (blk < 16) {
        // ========== qu quarter: 16 users x 64 cols (1 N-tile/wave) ==========
        int q = blk >> 2, co = (blk & 3) * 64, b0 = q * 16;
        // (1) issue the big weight fetch FIRST (stays in flight during staging)
        int col = co + w * 16 + (l & 15);
        float4 fb[8][2];
        #pragma unroll
        for (int kt = 0; kt < 8; ++kt) {
            const float* Bp = Wq + (size_t)col * 512 + kt * 32 + eo;
            fb[kt][0] = *(const float4*)Bp; fb[kt][1] = *(const float4*)(Bp + 4);
        }
        // (2) stage 16 user rows into A-frags
        for (int u = tid; u < 512; u += 256) {
            int r = u >> 5, e0 = (u & 31) * 8;
            const float* src = user_pref + (size_t)user[b0 + r] * 256 + e0;
            float4 f0 = *(const float4*)src, f1 = *(const float4*)(src + 4);
            unsigned* dst = &sA[(((e0 >> 5) * 2) * 64 + (r & 15) + 16 * ((e0 >> 3) & 3)) * 4];
            dst[0] = packbf(f0.x, f0.y); dst[1] = packbf(f0.z, f0.w);
            dst[2] = packbf(f1.x, f1.y); dst[3] = packbf(f1.z, f1.w);
        }
        __syncthreads();
        f32x4 acc = (f32x4)0.f;
        #pragma unroll
        for (int kt = 0; kt < 8; ++kt) {
            bf16x8 afr = __builtin_bit_cast(bf16x8, *(const int4*)&sA[((kt * 2) * 64 + l) * 4]);
            acc = __builtin_amdgcn_mfma_f32_16x16x32_bf16(afr, cvt8(fb[kt][0], fb[kt][1]), acc, 0, 0, 0);
        }
        int row = (l >> 4) * 4;
        #pragma unroll
        for (int r = 0; r < 4; ++r)
            ws[QU_OFF + (size_t)(b0 + row + r) * 256 + col] = acc[r];
        return;
    }

    if (blk < 20) {
        // ============ qk-chain h: qt_h, kk_h -> ET[t'][h*24+t] ============
        int h = blk - 16;
        int j = h * 64 + w * 16 + (l & 15);          // head-dim col
        // (1) weight loads first
        float4 fa[8][2], fc[8][2];
        #pragma unroll
        for (int kt = 0; kt < 8; ++kt) {
            const float* Bq = Wq + (size_t)j * 512 + 256 + kt * 32 + eo;
            const float* Bk = Wk + (size_t)j * 256 + kt * 32 + eo;
            fa[kt][0] = *(const float4*)Bq; fa[kt][1] = *(const float4*)(Bq + 4);
            fc[kt][0] = *(const float4*)Bk; fc[kt][1] = *(const float4*)(Bk + 4);
        }
        // (2) stage ts[24][256] as A-frags
        for (int u = tid; u < 768; u += 256) {
            int r = u >> 5, e0 = (u & 31) * 8;
            const float* src = ts + r * 256 + e0;
            float4 f0 = *(const float4*)src, f1 = *(const float4*)(src + 4);
            unsigned* dst = &sA[(((e0 >> 5) * 2 + (r >> 4)) * 64 + (r & 15) + 16 * ((e0 >> 3) & 3)) * 4];
            dst[0] = packbf(f0.x, f0.y); dst[1] = packbf(f0.z, f0.w);
            dst[2] = packbf(f1.x, f1.y); dst[3] = packbf(f1.z, f1.w);
        }
        __syncthreads();
        f32x4 aca[2] = {(f32x4)0.f, (f32x4)0.f};
        f32x4 acb[2] = {(f32x4)0.f, (f32x4)0.f};
        #pragma unroll
        for (int kt = 0; kt < 8; ++kt) {
            bf16x8 bq8 = cvt8(fa[kt][0], fa[kt][1]);
            bf16x8 bk8 = cvt8(fc[kt][0], fc[kt][1]);
            #pragma unroll
            for (int mt = 0; mt < 2; ++mt) {
                bf16x8 afr = __builtin_bit_cast(bf16x8, *(const int4*)&sA[((kt * 2 + mt) * 64 + l) * 4]);
                aca[mt] = __builtin_amdgcn_mfma_f32_16x16x32_bf16(afr, bq8, aca[mt], 0, 0, 0);
                acb[mt] = __builtin_amdgcn_mfma_f32_16x16x32_bf16(afr, bk8, acb[mt], 0, 0, 0);
            }
        }
        float bqv = bq[j], bkv = bk[j];
        int hd = w * 16 + (l & 15);
        #pragma unroll
        for (int mt = 0; mt < 2; ++mt) {
            int t0 = mt * 16 + (l >> 4) * 4;
            #pragma unroll
            for (int r = 0; r < 4; ++r) {
                int t = t0 + r;
                if (t < 24) {
                    sM1[t * 68 + hd] = aca[mt][r] + bqv;
                    float kv = acb[mt][r] + bkv;
                    sM2[t * 68 + hd] = kv;
                    ws[KK_OFF + (h * 24 + t) * 64 + hd] = kv;
                }
            }
        }
        __syncthreads();
        for (int u = tid; u < 576; u += 256) {       // ET: 24x24 dot-64
            int tp = u / 24, t = u - tp * 24;
            const float4* qp4 = (const float4*)&sM1[tp * 68];
            const float4* kp4 = (const float4*)&sM2[t * 68];
            float s = 0.f;
            #pragma unroll
            for (int i = 0; i < 16; ++i) s = dot4(qp4[i], kp4[i], s);
            ws[ET_OFF + tp * 96 + h * 24 + t] = expf(s * 0.125f);
        }
        return;
    }

    // ============== v-chain h: vv_h -> vW_h -> vWB (B-frag) ==============
    {
        int h = blk - 20;
        int jv = h * 64 + w * 16 + (l & 15);
        // (1) ALL weight loads first (Wv for GEMM1, Wu for GEMM2)
        float4 fv[8][2];
        #pragma unroll
        for (int kt = 0; kt < 8; ++kt) {
            const float* Bv = Wv + (size_t)jv * 256 + kt * 32 + eo;
            fv[kt][0] = *(const float4*)Bv; fv[kt][1] = *(const float4*)(Bv + 4);
        }
        float4 fu[2][4][2];
        #pragma unroll
        for (int kt2 = 0; kt2 < 2; ++kt2) {
            int k0 = kt2 * 32 + eo;
            #pragma unroll
            for (int q = 0; q < 4; ++q) {
                int d = (w * 4 + q) * 16 + (l & 15);
                const float* Bu = Wu + (size_t)d * 256 + h * 64 + k0;
                fu[kt2][q][0] = *(const float4*)Bu; fu[kt2][q][1] = *(const float4*)(Bu + 4);
            }
        }
        // (2) stage ts as A-frags
        for (int u = tid; u < 768; u += 256) {
            int r = u >> 5, e0 = (u & 31) * 8;
            const float* src = ts + r * 256 + e0;
            float4 f0 = *(const float4*)src, f1 = *(const float4*)(src + 4);
            unsigned* dst = &sA[(((e0 >> 5) * 2 + (r >> 4)) * 64 + (r & 15) + 16 * ((e0 >> 3) & 3)) * 4];
            dst[0] = packbf(f0.x, f0.y); dst[1] = packbf(f0.z, f0.w);
            dst[2] = packbf(f1.x, f1.y); dst[3] = packbf(f1.z, f1.w);
        }
        __syncthreads();
        f32x4 acv[2] = {(f32x4)0.f, (f32x4)0.f};
        #pragma unroll
        for (int kt = 0; kt < 8; ++kt) {
            bf16x8 bv8 = cvt8(fv[kt][0], fv[kt][1]);
            #pragma unroll
            for (int mt = 0; mt < 2; ++mt) {
                bf16x8 afr = __builtin_bit_cast(bf16x8, *(const int4*)&sA[((kt * 2 + mt) * 64 + l) * 4]);
                acv[mt] = __builtin_amdgcn_mfma_f32_16x16x32_bf16(afr, bv8, acv[mt], 0, 0, 0);
            }
        }
        float bvv = bv[jv];
        int hd = w * 16 + (l & 15);
        #pragma unroll
        for (int mt = 0; mt < 2; ++mt) {
            int t0 = mt * 16 + (l >> 4) * 4;
            #pragma unroll
            for (int r = 0; r < 4; ++r)
                if (t0 + r < 24) sM1[(t0 + r) * 68 + hd] = acv[mt][r] + bvv;
        }
        __syncthreads();
        // GEMM2: vW = vv[24(p32) x 64] @ WuCols^T -> vWB (B-frag layout)
        f32x4 ac2[2][4];
        #pragma unroll
        for (int mt = 0; mt < 2; ++mt)
            #pragma unroll
            for (int q = 0; q < 4; ++q) ac2[mt][q] = (f32x4)0.f;
        #pragma unroll
        for (int kt2 = 0; kt2 < 2; ++kt2) {
            int k0 = kt2 * 32 + eo;
            bf16x8 a2[2];
            #pragma unroll
            for (int mt = 0; mt < 2; ++mt) {
                int m = mt * 16 + (l & 15);
                float4 g0 = *(const float4*)&sM1[m * 68 + k0];
                float4 g1 = *(const float4*)&sM1[m * 68 + k0 + 4];
                a2[mt] = cvt8(g0, g1);
            }
            #pragma unroll
            for (int q = 0; q < 4; ++q) {
                bf16x8 bu8 = cvt8(fu[kt2][q][0], fu[kt2][q][1]);
                #pragma unroll
                for (int mt = 0; mt < 2; ++mt)
                    ac2[mt][q] = __builtin_amdgcn_mfma_f32_16x16x32_bf16(a2[mt], bu8, ac2[mt][q], 0, 0, 0);
            }
        }
        unsigned* vwb = (unsigned*)(ws + VWB_OFF);
        #pragma unroll
        for (int mt = 0; mt < 2; ++mt) {
            int t0 = mt * 16 + (l >> 4) * 4;
            if (t0 < 24) {
                #pragma unroll
                for (int q = 0; q < 4; ++q) {
                    int d = (w * 4 + q) * 16 + (l & 15);
                    #pragma unroll
                    for (int pp = 0; pp < 2; ++pp) {
                        int ht = h * 24 + t0 + pp * 2;       // even
                        unsigned pk = packbf(ac2[mt][q][pp * 2], ac2[mt][q][pp * 2 + 1]);
                        int ktC = ht >> 5, ntC = d >> 4;
                        int lgC = (ht >> 3) & 3, jhC = (ht & 7) >> 1;
                        vwb[(ktC * 16 + ntC) * 256 + ((d & 15) + 16 * lgC) * 4 + jhC] = pk;
                    }
                }
            }
        }
    }
}

// ---------- K2: 512 blocks x 256 thr (2/CU); prefetch-first; NT vec stores ----------
__global__ __launch_bounds__(256, 2) void attn_mfma(
    const int* __restrict__ hour, const int* __restrict__ hour_mask,
    const float* __restrict__ ws, const float* __restrict__ bu,
    float* __restrict__ out)
{
    const float* ET = ws + ET_OFF;
    __shared__ int4 A_lds[12 * 64];                    // 12 KB
    __shared__ float EU_s[96];
    __shared__ __align__(16) float stg[4 * 1088];      // 4 waves x [16][68] f32
    int tid = threadIdx.x, w = tid >> 6, l = tid & 63; // w = ns quarter
    int nb = blockIdx.x * 64;                 // 64 tokens/block, same b
    int b = nb >> 9;

    // ---- (1) longest-latency loads first: hour, mask (nontemporal) ----
    int tok = tid >> 2, h = tid & 3, n = nb + tok;
    int th = hour[n];
    const i32x4* mp = (const i32x4*)(hour_mask + (long long)n * 24);
    i32x4 msk[6];
    #pragma unroll
    for (int q = 0; q < 6; ++q) msk[q] = __builtin_nontemporal_load(mp + q);
    // ---- (2) B fragments (L2-resident table) ----
    const int4* Bg = (const int4*)(ws + VWB_OFF);
    int4 breg[12];
    #pragma unroll
    for (int kt = 0; kt < 3; ++kt)
        #pragma unroll
        for (int q = 0; q < 4; ++q)
            breg[kt * 4 + q] = Bg[(kt * 16 + w * 4 + q) * 64 + l];
    // ---- (3) EU[ht] for this block's b ----
    if (tid < 96) {
        const f32x4* qp = (const f32x4*)(ws + QU_OFF + b * 256 + (tid / 24) * 64);
        const f32x4* kp = (const f32x4*)(ws + KK_OFF + tid * 64);
        float s = 0.f;
        #pragma unroll
        for (int i = 0; i < 16; ++i) s = dot4v(qp[i], kp[i], s);
        EU_s[tid] = expf(s * 0.125f);
    }
    // ---- (4) ET row ----
    const f32x4* ETp = (const f32x4*)(ET + th * 96 + h * 24);
    f32x4 fET[6];
    #pragma unroll
    for (int q = 0; q < 6; ++q) fET[q] = ETp[q];
    __syncthreads();
    // ---- (5) softmax (no exp) -> bf16 A-fragments in LDS ----
    {
        const f32x4* EUp = (const f32x4*)(EU_s + h * 24);
        float p[24]; float ssum = 0.f;
        #pragma unroll
        for (int q = 0; q < 6; ++q) {
            f32x4 e = EUp[q]; f32x4 f = fET[q]; i32x4 mm = msk[q];
            float v0 = (mm[0] != 0) ? 0.f : e[0] * f[0];
            float v1 = (mm[1] != 0) ? 0.f : e[1] * f[1];
            float v2 = (mm[2] != 0) ? 0.f : e[2] * f[2];
            float v3 = (mm[3] != 0) ? 0.f : e[3] * f[3];
            p[q*4+0] = v0; p[q*4+1] = v1; p[q*4+2] = v2; p[q*4+3] = v3;
            ssum += (v0 + v1) + (v2 + v3);
        }
        float r = 1.0f / ssum;
        int mt = tok >> 4, tl = tok & 15;
        #pragma unroll
        for (int tp = 0; tp < 12; ++tp) {
            int ht = h * 24 + tp * 2;             // even; pair (ht, ht+1)
            unsigned pack = packbf(p[tp*2] * r, p[tp*2+1] * r);
            int kt = ht >> 5, lg = (ht >> 3) & 3, jh = (ht & 7) >> 1;
            ((unsigned*)A_lds)[((kt * 4 + mt) * 64 + tl + 16 * lg) * 4 + jh] = pack;
        }
    }
    __syncthreads();
    // ---- (6) wave w: 4 M-tiles x 4 N-tiles x 3 K-chunks MFMA ----
    bf16x8 afr[3][4];
    #pragma unroll
    for (int kt = 0; kt < 3; ++kt)
        #pragma unroll
        for (int q = 0; q < 4; ++q)
            afr[kt][q] = __builtin_bit_cast(bf16x8, A_lds[(kt * 4 + q) * 64 + l]);
    f32x4 acc[4][4];
    #pragma unroll
    for (int mt = 0; mt < 4; ++mt)
        #pragma unroll
        for (int q = 0; q < 4; ++q) acc[mt][q] = (f32x4)0.f;
    #pragma unroll
    for (int kt = 0; kt < 3; ++kt)
        #pragma unroll
        for (int mt = 0; mt < 4; ++mt)
            #pragma unroll
            for (int q = 0; q < 4; ++q)
                acc[mt][q] = __builtin_amdgcn_mfma_f32_16x16x32_bf16(
                    afr[kt][mt], __builtin_bit_cast(bf16x8, breg[kt * 4 + q]),
                    acc[mt][q], 0, 0, 0);
    // ---- (7) epilogue: per-wave LDS transpose -> +bu -> NT f32x4 stores ----
    // write: S[row=(l>>4)*4+r][col=q*16+(l&15)] = acc[mt][q][r]
    // read : lane l -> row=l>>2, 4 vecs at col=i*16+(l&3)*4  (bijective, r8-verified)
    float* sp = stg + w * 1088;
    int rr = l >> 2, cg = l & 3;
    f32x4 bu4[4];
    #pragma unroll
    for (int i = 0; i < 4; ++i)
        bu4[i] = *(const f32x4*)(bu + w * 64 + i * 16 + cg * 4);
    #pragma unroll
    for (int mt = 0; mt < 4; ++mt) {
        #pragma unroll
        for (int q = 0; q < 4; ++q)
            #pragma unroll
            for (int r = 0; r < 4; ++r)
                sp[((l >> 4) * 4 + r) * 68 + q * 16 + (l & 15)] = acc[mt][q][r];
        float* orow = out + (size_t)(nb + mt * 16 + rr) * 256 + w * 64;
        #pragma unroll
        for (int i = 0; i < 4; ++i) {
            f32x4 v = *(const f32x4*)(sp + rr * 68 + i * 16 + cg * 4);
            v = v + bu4[i];
            __builtin_nontemporal_store(v, (f32x4*)(orow + i * 16 + cg * 4));
        }
    }
}

extern "C" void kernel_launch(void* const* d_in, const int* in_sizes, int n_in,
                              void* d_out, int out_size, void* d_ws, size_t ws_size,
                              hipStream_t stream)
{
    const float* ts        = (const float*)d_in[0];
    const int*   user      = (const int*)  d_in[1];
    const int*   hour      = (const int*)  d_in[2];
    const int*   hour_mask = (const int*)  d_in[3];
    const float* user_pref = (const float*)d_in[4];
    const float* Wq        = (const float*)d_in[5];
    const float* bq        = (const float*)d_in[6];
    const float* Wk        = (const float*)d_in[7];
    const float* bk        = (const float*)d_in[8];
    const float* Wv        = (const float*)d_in[9];
    const float* bv        = (const float*)d_in[10];
    const float* Wu        = (const float*)d_in[11];
    const float* bu        = (const float*)d_in[12];
    float* ws  = (float*)d_ws;
    float* out = (float*)d_out;

    hipLaunchKernelGGL(precomp, dim3(24), dim3(256), 0, stream,
                       ts, user, user_pref, Wq, bq, Wk, bk, Wv, bv, Wu, ws);
    hipLaunchKernelGGL(attn_mfma, dim3(512), dim3(256), 0, stream,
                       hour, hour_mask, ws, bu, out);
}